// Round 1
// baseline (40.630 us; speedup 1.0000x reference)
//
#include <hip/hip_runtime.h>

#define BUCKET_MASK ((1u << 21) - 1u)

__global__ __launch_bounds__(256) void voxel_hash_kernel(
    const float* __restrict__ pts,
    const float* __restrict__ feats0,
    const float* __restrict__ feats1,
    float* __restrict__ out,
    int npts)
{
    int gid = blockIdx.x * 256 + threadIdx.x;
    int n   = gid >> 4;          // point index
    int sub = gid & 15;          // 0..15: which float4 of the 64-float output row
    if (n >= npts) return;

    int level = sub >> 3;        // 0 -> features0/res .24, 1 -> features1/res .12
    int chunk = sub & 7;         // float4 index within the 32-float feature row

    const float res = level ? 0.12f : 0.24f;
    const float* __restrict__ feats = level ? feats1 : feats0;

    // Load point (16 lanes broadcast same 3 floats from L1)
    float px = pts[n * 3 + 0];
    float py = pts[n * 3 + 1];
    float pz = pts[n * 3 + 2];

    // IEEE f32 divide to exactly match jnp (pts / float32(res))
    float qx = px / res, qy = py / res, qz = pz / res;
    float bx = floorf(qx), by = floorf(qy), bz = floorf(qz);
    float fx = qx - bx, fy = qy - by, fz = qz - bz;

    int ix = (int)bx, iy = (int)by, iz = (int)bz;

    // Hash in uint32: (x*P0 + y*P1 + z*P2) mod 2^21 == low-21-bits of mod-2^32 sum.
    unsigned hx0 = (unsigned)ix * 73856093u;
    unsigned hy0 = (unsigned)iy * 19349669u;
    unsigned hz0 = (unsigned)iz * 83492791u;
    unsigned hx1 = hx0 + 73856093u;
    unsigned hy1 = hy0 + 19349669u;
    unsigned hz1 = hz0 + 83492791u;

    float gx = 1.0f - fx, gy = 1.0f - fy, gz = 1.0f - fz;

    float4 acc = make_float4(0.0f, 0.0f, 0.0f, 0.0f);

    #pragma unroll
    for (int c = 0; c < 8; ++c) {
        unsigned h = ((c & 1) ? hx1 : hx0)
                   + ((c & 2) ? hy1 : hy0)
                   + ((c & 4) ? hz1 : hz0);
        unsigned vid = h & BUCKET_MASK;
        float w = ((c & 1) ? fx : gx) * ((c & 2) ? fy : gy) * ((c & 4) ? fz : gz);

        const float4 f = *reinterpret_cast<const float4*>(
            feats + (size_t)vid * 32u + (unsigned)chunk * 4u);
        acc.x += w * f.x;
        acc.y += w * f.y;
        acc.z += w * f.z;
        acc.w += w * f.w;
    }

    *reinterpret_cast<float4*>(out + (size_t)n * 64u + (unsigned)sub * 4u) = acc;
}

extern "C" void kernel_launch(void* const* d_in, const int* in_sizes, int n_in,
                              void* d_out, int out_size, void* d_ws, size_t ws_size,
                              hipStream_t stream) {
    const float* pts = (const float*)d_in[0];
    const float* f0  = (const float*)d_in[1];
    const float* f1  = (const float*)d_in[2];
    float* out = (float*)d_out;

    int npts = in_sizes[0] / 3;               // 262144
    long long threads = (long long)npts * 16; // 16 lanes per point
    int grid = (int)((threads + 255) / 256);

    voxel_hash_kernel<<<grid, 256, 0, stream>>>(pts, f0, f1, out, npts);
}